// Round 1
// baseline (363.417 us; speedup 1.0000x reference)
//
#include <hip/hip_runtime.h>
#include <cstddef>

// Problem constants
#define NN 512
#define DD 128
#define HH 4
#define LL 4
#define GHD 32
#define OUTD 128

// ws layout (float offsets)
static constexpr size_t OFF_EM  = 0;                              // [N][D]       edge_mean
static constexpr size_t OFF_ANF = OFF_EM  + (size_t)NN * DD;      // [H][N][D]    A @ node_feat
static constexpr size_t OFF_DEN = OFF_ANF + (size_t)HH * NN * DD; // [H][N]       denom
static constexpr size_t OFF_G   = OFF_DEN + (size_t)HH * NN;      // [H][L][N][GHD]  g_l
static constexpr size_t OFF_AG  = OFF_G   + (size_t)HH * LL * NN * GHD; // [H][3][N][GHD] A@g_k
// total ≈ 3.1 MB of f32

// ---------------------------------------------------------------------------
// Kernel 1: fused prep.
//   blocks [0, N):        edge_mean row b  (HBM-bound, 134 MB stream)
//   blocks [N, N+H*64):   A@node_feat (8 rows per block) + deg/denom
// ---------------------------------------------------------------------------
__global__ __launch_bounds__(256) void prep_kernel(
    const float* __restrict__ node_feat,
    const float* __restrict__ edge_feat,
    const float* __restrict__ adj,
    float* __restrict__ ws)
{
    const int t = threadIdx.x;
    const int b = blockIdx.x;

    __shared__ float4 red[256];          // edge_mean reduction
    __shared__ float  Arow[8][NN + 4];   // staged A rows (padded: bank spread)
    __shared__ float  dred[8][33];       // deg reduction

    if (b < NN) {
        // ---- edge_mean[b][:] = (1/N) * sum_j edge_feat[b][j][:] ----
        const int q = t & 31;   // float4 column (32 quads = 128 floats)
        const int g = t >> 5;   // j-group 0..7
        const float4* ef = reinterpret_cast<const float4*>(edge_feat)
                         + (size_t)b * NN * (DD / 4);
        float4 acc; acc.x = acc.y = acc.z = acc.w = 0.f;
        #pragma unroll 4
        for (int j = g; j < NN; j += 8) {
            float4 v = ef[(size_t)j * (DD / 4) + q];
            acc.x += v.x; acc.y += v.y; acc.z += v.z; acc.w += v.w;
        }
        red[t] = acc;
        __syncthreads();
        for (int s = 128; s >= 32; s >>= 1) {
            if (t < s) {
                float4 o = red[t + s], m = red[t];
                m.x += o.x; m.y += o.y; m.z += o.z; m.w += o.w;
                red[t] = m;
            }
            __syncthreads();
        }
        if (t < 32) {
            const float inv = 1.0f / (float)NN;
            float4 m = red[t];
            m.x *= inv; m.y *= inv; m.z *= inv; m.w *= inv;
            reinterpret_cast<float4*>(ws + OFF_EM + (size_t)b * DD)[t] = m;
        }
    } else {
        // ---- A@node_feat + denom for head h, rows r0..r0+7 ----
        const int bb = b - NN;
        const int h  = bb >> 6;
        const int r0 = (bb & 63) * 8;
        const float* A = adj + (size_t)h * NN * NN;

        for (int idx = t; idx < 8 * NN; idx += 256) {
            int rr = idx >> 9;
            int jj = idx & (NN - 1);
            Arow[rr][jj] = A[(size_t)(r0 + rr) * NN + jj];
        }
        __syncthreads();

        {   // deg -> denom
            const int rr = t >> 5, lane = t & 31;
            float s = 0.f;
            for (int j = lane; j < NN; j += 32) s += Arow[rr][j];
            dred[rr][lane] = s;
            __syncthreads();
            if (t < 8) {
                float d = 0.f;
                #pragma unroll 8
                for (int j = 0; j < 32; ++j) d += dred[t][j];
                ws[OFF_DEN + (size_t)h * NN + r0 + t] = d + (d == 0.f ? 1.f : 0.f);
            }
        }

        // A_nf: thread (rb = t>>7 in {0,1}, c = t&127); rows rb, rb+2, rb+4, rb+6
        const int c  = t & 127;
        const int rb = t >> 7;
        float a0 = 0.f, a1 = 0.f, a2 = 0.f, a3 = 0.f;
        #pragma unroll 4
        for (int j = 0; j < NN; ++j) {
            float nf = node_feat[(size_t)j * DD + c];
            a0 += Arow[rb + 0][j] * nf;
            a1 += Arow[rb + 2][j] * nf;
            a2 += Arow[rb + 4][j] * nf;
            a3 += Arow[rb + 6][j] * nf;
        }
        float* anf = ws + OFF_ANF + ((size_t)h * NN + r0) * DD;
        anf[(rb + 0) * DD + c] = a0;
        anf[(rb + 2) * DD + c] = a1;
        anf[(rb + 4) * DD + c] = a2;
        anf[(rb + 6) * DD + c] = a3;
    }
}

// ---------------------------------------------------------------------------
// Per-layer kernel: grid = H*64 blocks, 8 rows each, 256 threads.
// Thread (r = r0 + t/32, c = t%32) owns one output element.
//   step 1 (LAYER>0): Ag_{L-1}[r][c] = sum_j A[h][r][j] * g_{L-1}[j][c]
//   step 2: acc = edge_mean[r]@W_edge[h,L][:,c] + Anf[h][r]@Wn[:128,c]
//                 + sum_k Ag_k[r]@Wn[128+32k:,c]
//   g = relu(acc / denom)
// ---------------------------------------------------------------------------
template <int LAYER>
__global__ __launch_bounds__(256) void layer_kernel(
    const float* __restrict__ adj,
    const float* __restrict__ W_edge,
    const float* __restrict__ Wn,      // [H][128+32*LAYER][GHD]
    float* __restrict__ ws)
{
    constexpr int KIN = DD + GHD * LAYER;
    const int b  = blockIdx.x;
    const int h  = b >> 6;
    const int r0 = (b & 63) * 8;
    const int t  = threadIdx.x;
    const int rr = t >> 5;
    const int r  = r0 + rr;
    const int c  = t & 31;

    const float* em  = ws + OFF_EM;
    const float* anf = ws + OFF_ANF;
    const float* den = ws + OFF_DEN;
    float* G  = ws + OFF_G;
    float* AG = ws + OFF_AG;

    __shared__ float agl[8][GHD];

    if (LAYER > 0) {
        const float4* A4 = reinterpret_cast<const float4*>(
            adj + ((size_t)h * NN + r) * NN);
        const float* gp = G + (((size_t)h * LL + (LAYER - 1)) * NN) * GHD;
        float s0 = 0.f, s1 = 0.f, s2 = 0.f, s3 = 0.f;
        #pragma unroll 4
        for (int j4 = 0; j4 < NN / 4; ++j4) {
            float4 a = A4[j4];
            const float* gpj = gp + (size_t)j4 * 4 * GHD + c;
            s0 += a.x * gpj[0 * GHD];
            s1 += a.y * gpj[1 * GHD];
            s2 += a.z * gpj[2 * GHD];
            s3 += a.w * gpj[3 * GHD];
        }
        float ag = (s0 + s1) + (s2 + s3);
        agl[rr][c] = ag;
        AG[(((size_t)h * 3 + (LAYER - 1)) * NN + r) * GHD + c] = ag;
    }
    __syncthreads();

    float acc = 0.f;
    {   // e_out
        const float* We  = W_edge + (((size_t)h * LL + LAYER) * DD) * GHD;
        const float4* e4 = reinterpret_cast<const float4*>(em + (size_t)r * DD);
        #pragma unroll 4
        for (int k4 = 0; k4 < DD / 4; ++k4) {
            float4 e = e4[k4];
            const float* w = We + (size_t)k4 * 4 * GHD + c;
            acc += e.x * w[0 * GHD] + e.y * w[1 * GHD]
                 + e.z * w[2 * GHD] + e.w * w[3 * GHD];
        }
    }
    {   // n_out = [Anf | Ag0..Ag_{L-1}] @ Wn
        const float* Wnl = Wn + (size_t)h * KIN * GHD;
        const float4* a4 = reinterpret_cast<const float4*>(
            anf + ((size_t)h * NN + r) * DD);
        #pragma unroll 4
        for (int k4 = 0; k4 < DD / 4; ++k4) {
            float4 e = a4[k4];
            const float* w = Wnl + (size_t)k4 * 4 * GHD + c;
            acc += e.x * w[0 * GHD] + e.y * w[1 * GHD]
                 + e.z * w[2 * GHD] + e.w * w[3 * GHD];
        }
        #pragma unroll
        for (int kk = 0; kk < LAYER; ++kk) {
            const float* w = Wnl + (size_t)(DD + kk * GHD) * GHD + c;
            if (kk == LAYER - 1) {
                #pragma unroll 8
                for (int m = 0; m < GHD; ++m) acc += agl[rr][m] * w[m * GHD];
            } else {
                const float* agk = AG + (((size_t)h * 3 + kk) * NN + r) * GHD;
                #pragma unroll 8
                for (int m = 0; m < GHD; ++m) acc += agk[m] * w[m * GHD];
            }
        }
    }

    float dn = den[(size_t)h * NN + r];
    float gv = acc / dn;
    gv = gv > 0.f ? gv : 0.f;
    G[(((size_t)h * LL + LAYER) * NN + r) * GHD + c] = gv;
}

// ---------------------------------------------------------------------------
// Final: out[n][o] = b[o] + sum_{h,l,c} (g_l[h][n][c] + nf[n][l*32+c]) * W_lin[h*128+l*32+c][o]
// grid = 256 blocks × 2 rows, 256 threads (rr = t>>7, o = t&127)
// ---------------------------------------------------------------------------
__global__ __launch_bounds__(256) void final_kernel(
    const float* __restrict__ node_feat,
    const float* __restrict__ W_lin,
    const float* __restrict__ b_lin,
    const float* __restrict__ ws,
    float* __restrict__ out)
{
    const int b = blockIdx.x;
    const int t = threadIdx.x;
    const int n = b * 2 + (t >> 7);
    const int o = t & 127;
    const float* G   = ws + OFF_G;
    const float* nfr = node_feat + (size_t)n * DD;

    float acc = b_lin[o];
    #pragma unroll
    for (int h = 0; h < HH; ++h) {
        #pragma unroll
        for (int l = 0; l < LL; ++l) {
            const float* gr = G + (((size_t)h * LL + l) * NN + n) * GHD;
            const float* w  = W_lin + (size_t)(h * DD + l * GHD) * OUTD + o;
            #pragma unroll 8
            for (int cc = 0; cc < GHD; ++cc) {
                float ah = gr[cc] + nfr[l * GHD + cc];
                acc += ah * w[(size_t)cc * OUTD];
            }
        }
    }
    out[(size_t)n * OUTD + o] = acc;
}

// ---------------------------------------------------------------------------
extern "C" void kernel_launch(void* const* d_in, const int* in_sizes, int n_in,
                              void* d_out, int out_size, void* d_ws, size_t ws_size,
                              hipStream_t stream)
{
    const float* node_feat = (const float*)d_in[0];
    const float* edge_feat = (const float*)d_in[1];
    const float* adj       = (const float*)d_in[2];
    const float* W_edge    = (const float*)d_in[3];
    const float* Wn0       = (const float*)d_in[4];
    const float* Wn1       = (const float*)d_in[5];
    const float* Wn2       = (const float*)d_in[6];
    const float* Wn3       = (const float*)d_in[7];
    const float* W_lin     = (const float*)d_in[8];
    const float* b_lin     = (const float*)d_in[9];
    float* out = (float*)d_out;
    float* ws  = (float*)d_ws;

    hipLaunchKernelGGL(prep_kernel, dim3(NN + HH * 64), dim3(256), 0, stream,
                       node_feat, edge_feat, adj, ws);
    hipLaunchKernelGGL(layer_kernel<0>, dim3(HH * 64), dim3(256), 0, stream,
                       adj, W_edge, Wn0, ws);
    hipLaunchKernelGGL(layer_kernel<1>, dim3(HH * 64), dim3(256), 0, stream,
                       adj, W_edge, Wn1, ws);
    hipLaunchKernelGGL(layer_kernel<2>, dim3(HH * 64), dim3(256), 0, stream,
                       adj, W_edge, Wn2, ws);
    hipLaunchKernelGGL(layer_kernel<3>, dim3(HH * 64), dim3(256), 0, stream,
                       adj, W_edge, Wn3, ws);
    hipLaunchKernelGGL(final_kernel, dim3(NN / 2), dim3(256), 0, stream,
                       node_feat, W_lin, b_lin, ws, out);
}

// Round 3
// 330.843 us; speedup vs baseline: 1.0985x; 1.0985x over previous
//
#include <hip/hip_runtime.h>
#include <cstddef>

// Problem constants
#define NN 512
#define DD 128
#define HH 4
#define LL 4
#define GHD 32
#define OUTD 128

// ws layout (float offsets)
static constexpr size_t OFF_EP  = 0;                               // [4][N][D]  edge j-quarter partials
static constexpr size_t OFF_ANF = OFF_EP  + (size_t)4 * NN * DD;   // [H][N][D]  A @ node_feat
static constexpr size_t OFF_DEN = OFF_ANF + (size_t)HH * NN * DD;  // [H][N]
static constexpr size_t OFF_EO  = OFF_DEN + (size_t)HH * NN;       // [H][L][N][GHD]  edge_mean @ W_edge
static constexpr size_t OFF_G   = OFF_EO  + (size_t)HH * LL * NN * GHD; // [H][L][N][GHD]
static constexpr size_t OFF_AG  = OFF_G   + (size_t)HH * LL * NN * GHD; // [H][3][N][GHD]
// total ≈ 5.0 MB of f32

// ---------------------------------------------------------------------------
// K1 prep: grid = 512 + 2048 blocks x 256.
//   b <  512 : Anf + deg for (h = b>>7, rows (b&127)*4 .. +3)   [dispatched first]
//   b >= 512 : edge partial for (r = (b-512)>>2, j-quarter (b-512)&3)
// ---------------------------------------------------------------------------
__global__ __launch_bounds__(256) void prep_kernel(
    const float* __restrict__ node_feat,
    const float* __restrict__ edge_feat,
    const float* __restrict__ adj,
    float* __restrict__ ws)
{
    const int t = threadIdx.x;
    const int b = blockIdx.x;
    __shared__ __align__(16) float smem[4 * NN + 256];  // 2304 floats

    if (b >= 512) {
        // ---- edge partial: sum over 128 j-rows of a 64 KB contiguous slab ----
        const int bb = b - 512;
        const int r  = bb >> 2;
        const int jq = bb & 3;
        const int q  = t & 31;   // float4 column
        const int g  = t >> 5;   // j-subgroup
        const float4* ef = reinterpret_cast<const float4*>(edge_feat)
                         + ((size_t)r * NN + (size_t)jq * 128) * (DD / 4);
        float4 acc; acc.x = acc.y = acc.z = acc.w = 0.f;
        #pragma unroll
        for (int k = 0; k < 16; ++k) {
            float4 v = ef[(size_t)(g + 8 * k) * (DD / 4) + q];
            acc.x += v.x; acc.y += v.y; acc.z += v.z; acc.w += v.w;
        }
        float4* red = reinterpret_cast<float4*>(smem);
        red[t] = acc;
        __syncthreads();
        for (int s = 128; s >= 32; s >>= 1) {
            if (t < s) {
                float4 o = red[t + s], m = red[t];
                m.x += o.x; m.y += o.y; m.z += o.z; m.w += o.w;
                red[t] = m;
            }
            __syncthreads();
        }
        if (t < 32)
            reinterpret_cast<float4*>(ws + OFF_EP + ((size_t)jq * NN + r) * DD)[t] = red[t];
    } else {
        // ---- Anf + deg ----
        const int h  = b >> 7;
        const int r0 = (b & 127) * 4;
        const float* A = adj + (size_t)h * NN * NN;
        float* Arow = smem;            // [4][512]
        float* dred = smem + 4 * NN;   // [256]

        for (int idx = t; idx < 4 * NN; idx += 256)
            Arow[idx] = A[(size_t)r0 * NN + idx];   // rows r0..r0+3 contiguous
        __syncthreads();

        {   // deg -> denom
            const int rr = t >> 6, lane = t & 63;
            float s = 0.f;
            #pragma unroll 8
            for (int j = lane; j < NN; j += 64) s += Arow[rr * NN + j];
            dred[t] = s;
            __syncthreads();
            if (t < 4) {
                float d = 0.f;
                for (int j = 0; j < 64; ++j) d += dred[t * 64 + j];
                ws[OFF_DEN + (size_t)h * NN + r0 + t] = d + (d == 0.f ? 1.f : 0.f);
            }
        }

        // Anf rows rb, rb+2 (rb = t>>7), col c = t&127
        const int c  = t & 127;
        const int rb = t >> 7;
        float a0 = 0.f, a1 = 0.f;
        #pragma unroll 4
        for (int j = 0; j < NN; ++j) {
            float nf = node_feat[(size_t)j * DD + c];
            a0 += Arow[(rb + 0) * NN + j] * nf;
            a1 += Arow[(rb + 2) * NN + j] * nf;
        }
        float* anf = ws + OFF_ANF + ((size_t)h * NN + r0) * DD;
        anf[(rb + 0) * DD + c] = a0;
        anf[(rb + 2) * DD + c] = a1;
    }
}

// ---------------------------------------------------------------------------
// K2 eout: all 16 e_out[h,l] panels. grid = 512 blocks (hl = b>>5, 16 rows).
// Phase 1: finish edge_mean for 16 rows into LDS. Phase 2: dot with W_edge.
// ---------------------------------------------------------------------------
__global__ __launch_bounds__(256) void eout_kernel(
    const float* __restrict__ W_edge,
    float* __restrict__ ws)
{
    const int b  = blockIdx.x;
    const int rg = b & 31;       // row group
    const int hl = b >> 5;       // h*4 + l
    const int r0 = rg * 16;
    const int t  = threadIdx.x;
    __shared__ float em[16 * DD];

    const float* P = ws + OFF_EP;
    for (int idx = t; idx < 16 * DD; idx += 256) {
        int r = r0 + (idx >> 7), k = idx & 127;
        size_t o = (size_t)r * DD + k;
        em[idx] = (P[o] + P[(size_t)NN * DD + o]
                 + P[2 * (size_t)NN * DD + o] + P[3 * (size_t)NN * DD + o])
                * (1.0f / (float)NN);
    }
    __syncthreads();

    const int c  = t & 31;
    const int rr = t >> 5;       // rows rr and rr+8
    const float* We = W_edge + (size_t)hl * DD * GHD;
    float s0 = 0.f, s1 = 0.f;
    #pragma unroll 4
    for (int k = 0; k < DD; ++k) {
        float w = We[(size_t)k * GHD + c];
        s0 += em[rr * DD + k] * w;
        s1 += em[(rr + 8) * DD + k] * w;
    }
    float* eo = ws + OFF_EO + ((size_t)hl * NN + r0) * GHD;
    eo[(size_t)rr * GHD + c]       = s0;
    eo[(size_t)(rr + 8) * GHD + c] = s1;
}

// ---------------------------------------------------------------------------
// K3..K6 layer L: grid = 1024 blocks (h = b>>8, rows (b&255)*2 .. +1).
// Threads: rr = t>>7 (row), sub = (t>>5)&3 (k/j quarter), c = t&31.
// ---------------------------------------------------------------------------
template <int L>
__global__ __launch_bounds__(256) void layer_kernel(
    const float* __restrict__ adj,
    const float* __restrict__ Wn,   // [H][128+32*L][GHD]
    float* __restrict__ ws)
{
    constexpr int KIN = DD + GHD * L;
    const int b   = blockIdx.x;
    const int h   = b >> 8;
    const int r0  = (b & 255) * 2;
    const int t   = threadIdx.x;
    const int rr  = t >> 7;
    const int sub = (t >> 5) & 3;
    const int c   = t & 31;
    const int r   = r0 + rr;

    const float* anf = ws + OFF_ANF;
    const float* den = ws + OFF_DEN;
    const float* eo  = ws + OFF_EO;
    float* G  = ws + OFF_G;
    float* AG = ws + OFF_AG;

    __shared__ float smem[256 + 64 + 256];
    float* agp = smem;        // Ag partials
    float* agl = smem + 256;  // [2][32] fresh Ag
    float* pp  = smem + 320;  // p partials

    if (L > 0) {
        const float4* A4 = reinterpret_cast<const float4*>(
            adj + ((size_t)h * NN + r) * NN);
        const float* gp = G + (((size_t)h * LL + (L - 1)) * NN) * GHD;
        float s = 0.f;
        #pragma unroll 4
        for (int j4 = sub * 32; j4 < sub * 32 + 32; ++j4) {
            float4 a = A4[j4];
            const float* gj = gp + (size_t)j4 * 4 * GHD + c;
            s += a.x * gj[0] + a.y * gj[GHD] + a.z * gj[2 * GHD] + a.w * gj[3 * GHD];
        }
        agp[t] = s;
    }
    __syncthreads();
    if (L > 0 && sub == 0) {
        float ag = agp[rr * 128 + c] + agp[rr * 128 + 32 + c]
                 + agp[rr * 128 + 64 + c] + agp[rr * 128 + 96 + c];
        AG[(((size_t)h * 3 + (L - 1)) * NN + r) * GHD + c] = ag;
        agl[rr * GHD + c] = ag;
    }
    __syncthreads();

    float p = 0.f;
    {
        const float* Wnl = Wn + (size_t)h * KIN * GHD;
        const float* ar  = anf + ((size_t)h * NN + r) * DD;
        #pragma unroll 8
        for (int k = sub * 32; k < sub * 32 + 32; ++k)
            p += ar[k] * Wnl[(size_t)k * GHD + c];
        if (sub < L) {
            const float* agk = (sub == L - 1)
                ? (agl + rr * GHD)
                : (AG + (((size_t)h * 3 + sub) * NN + r) * GHD);
            const float* w = Wnl + (size_t)(DD + sub * GHD) * GHD + c;
            #pragma unroll 8
            for (int m = 0; m < GHD; ++m)
                p += agk[m] * w[(size_t)m * GHD];
        }
    }
    pp[t] = p;
    __syncthreads();
    if (sub == 0) {
        float tot = pp[rr * 128 + c] + pp[rr * 128 + 32 + c]
                  + pp[rr * 128 + 64 + c] + pp[rr * 128 + 96 + c]
                  + eo[(((size_t)h * LL + L) * NN + r) * GHD + c];
        float dn = den[(size_t)h * NN + r];
        float gv = tot / dn;
        gv = gv > 0.f ? gv : 0.f;
        G[(((size_t)h * LL + L) * NN + r) * GHD + c] = gv;
    }
}

// ---------------------------------------------------------------------------
// K7 final: grid = 1024 blocks (n = b>>1, o-half = b&1); ks = t>>6 splits heads.
// ---------------------------------------------------------------------------
__global__ __launch_bounds__(256) void final_kernel(
    const float* __restrict__ node_feat,
    const float* __restrict__ W_lin,
    const float* __restrict__ b_lin,
    const float* __restrict__ ws,
    float* __restrict__ out)
{
    const int b  = blockIdx.x;
    const int n  = b >> 1;
    const int oh = b & 1;
    const int t  = threadIdx.x;
    const int ol = t & 63;
    const int ks = t >> 6;
    const int o  = oh * 64 + ol;
    const float* G = ws + OFF_G;
    __shared__ float red[256];

    float p = 0.f;
    #pragma unroll
    for (int l = 0; l < LL; ++l) {
        const float* gr  = G + (((size_t)ks * LL + l) * NN + n) * GHD;
        const float* nfr = node_feat + (size_t)n * DD + l * GHD;
        const float* w   = W_lin + (size_t)(ks * DD + l * GHD) * OUTD + o;
        #pragma unroll 8
        for (int cc = 0; cc < GHD; ++cc)
            p += (gr[cc] + nfr[cc]) * w[(size_t)cc * OUTD];
    }
    red[t] = p;
    __syncthreads();
    if (ks == 0)
        out[(size_t)n * OUTD + o] =
            red[ol] + red[64 + ol] + red[128 + ol] + red[192 + ol] + b_lin[o];
}

// ---------------------------------------------------------------------------
extern "C" void kernel_launch(void* const* d_in, const int* in_sizes, int n_in,
                              void* d_out, int out_size, void* d_ws, size_t ws_size,
                              hipStream_t stream)
{
    const float* node_feat = (const float*)d_in[0];
    const float* edge_feat = (const float*)d_in[1];
    const float* adj       = (const float*)d_in[2];
    const float* W_edge    = (const float*)d_in[3];
    const float* Wn0       = (const float*)d_in[4];
    const float* Wn1       = (const float*)d_in[5];
    const float* Wn2       = (const float*)d_in[6];
    const float* Wn3       = (const float*)d_in[7];
    const float* W_lin     = (const float*)d_in[8];
    const float* b_lin     = (const float*)d_in[9];
    float* out = (float*)d_out;
    float* ws  = (float*)d_ws;

    hipLaunchKernelGGL(prep_kernel, dim3(512 + 2048), dim3(256), 0, stream,
                       node_feat, edge_feat, adj, ws);
    hipLaunchKernelGGL(eout_kernel, dim3(512), dim3(256), 0, stream, W_edge, ws);
    hipLaunchKernelGGL(layer_kernel<0>, dim3(1024), dim3(256), 0, stream, adj, Wn0, ws);
    hipLaunchKernelGGL(layer_kernel<1>, dim3(1024), dim3(256), 0, stream, adj, Wn1, ws);
    hipLaunchKernelGGL(layer_kernel<2>, dim3(1024), dim3(256), 0, stream, adj, Wn2, ws);
    hipLaunchKernelGGL(layer_kernel<3>, dim3(1024), dim3(256), 0, stream, adj, Wn3, ws);
    hipLaunchKernelGGL(final_kernel, dim3(1024), dim3(256), 0, stream,
                       node_feat, W_lin, b_lin, ws, out);
}